// Round 8
// baseline (525.338 us; speedup 1.0000x reference)
//
#include <hip/hip_runtime.h>
#include <math.h>

// FrankWolfePolicyImprovement, fused: 4096 problems, one wave (64 lanes) each.
// Phases (single kernel, A resident in LDS throughout):
//   1. anchor QP  (Schur-reduced d=68 ADMM, 80 it, Sinv rows in VGPRs)
//   2. tanh MLP gradient
//   3. LMO QP on row-normalized A (normalization folded into registers)
//   4. blend + store
//
// Round-14: final DS-census micro-pass (all bit-identical, zero reg cost):
//  (a) sweep alpha folded into the j=0 b128 read (lsrow[0] == rp0.x; j=0's
//      .x was unused in updates): 18 -> 17 DS/pivot, -128 DS/problem.
//  (b) acol re-normalization: acol still holds RAW A[k][t] from the anchor
//      phase -> acol[k] *= lsrn[k] with lsrn via 8 b128 broadcasts
//      (was 32 spread-b32 + 32 bcast-b32): -56 DS.
//  (c) rcp_r computed locally (every lane holds full pr after xor32 fold;
//      same ops = same bits); lsrn kept only for k-indexed consumers: -1 DS.
// Expected -1.9%. PRE-COMMIT: if <1% or regression, declare structural
// floor (DS-issue pipe ~90% duty at minimal op count for this decomposition).
//
// Measured-dead levers (do not retry):
//  - A-rows in VGPRs: reg file full (124/128 live at (64,4)); (64,3) starves
//    latency hiding (+20%), (64,4) spills via AGPR-split (FETCH 70MB->2GB).
//  - readlane broadcasts: SGPR RAW hazard ~12cyc unhidden, +21%. LDS b128
//    broadcast delivers 4 operands/issue-slot, latency hidden by 16 waves.
//  - occupancy: grid = exactly 16 blocks/CU = LDS capacity.
//  - iteration truncation: ref is the 80-it ITERATE; 64-it LMO fails 3.2x.
//    ITERATION COUNTS PINNED: anchor=80, LMO=80.
//  - Woodbury/32x32, B=A*Sinv precompute, bigger LDS: all add more DS or
//    halve occupancy (audited rounds 13-14).
//
//  - NO dynamic indexing into register arrays (demotes array to scratch/AGPR).
//  - All wave-internal broadcasts on the LDS pipe (wave-uniform float4 reads).
//  - WAVE_FENCE instead of __syncthreads: single-wave blocks + per-wave
//    in-order DS (HW-verified rounds 7-9).
//  - xor-32 folds on VALU via v_permlane32_swap_b32 (round-13 win).
//  - Inversion via symmetric sweep operator: pivot row == pivot col, lane-local
//    after rotation; broadcast = 1 conflict-free ds_write + 16 b128 reads.
//    After 64 sweeps W = -S^-1; minus folds into the x-update FMA modifier.

constexpr float SIG  = 1e-6f;
constexpr float C2   = 1.0f / (4.0f + 1e-6f);   // 1/(4+sigma): slack Schur diag
constexpr int   ITRS = 80;                       // anchor ADMM iterations (pinned)
constexpr int   ITRS_LMO = 80;                   // LMO ADMM iterations (pinned)
constexpr int   LDA  = 68;                       // LDS stride for A (16B-aligned rows)

// Compiler-only ordering fence. Valid because each block is ONE wave and DS
// ops execute in order within a wave (RAW through LDS needs no barrier).
#define WAVE_FENCE() asm volatile("" ::: "memory")

typedef unsigned int uint2v __attribute__((ext_vector_type(2)));

__device__ __forceinline__ float rl(float v, int lane) {
  return __uint_as_float(__builtin_amdgcn_readlane(__float_as_uint(v), lane));
}

// Full-wave lane<->lane+32 fold on the VALU pipe (v_permlane32_swap_b32).
// With equal operands the swap yields [v_lo,v_lo] and [v_hi,v_hi]; their sum
// equals v + shfl_xor(v,32) on every lane, bit-identically.
__device__ __forceinline__ float xor32_sum(float v) {
  unsigned u = __float_as_uint(v);
  uint2v rr = __builtin_amdgcn_permlane32_swap(u, u, false, false);
  return __uint_as_float(rr[0]) + __uint_as_float(rr[1]);
}

// v_rcp_f32 + one Newton step: ~full fp32 precision reciprocal.
__device__ __forceinline__ float rcp_nr(float x) {
  float r = __builtin_amdgcn_rcpf(x);
  return r * fmaf(-x, r, 2.0f);
}

// Symmetric sweep-operator inversion. Lane t holds row t (== col t) of the
// symmetric working matrix W, rotated so the current pivot is local index 0.
// After 64 sweeps: Cm[j] = -Sinv[t][j]. Single-wave blocks; cross-lane data
// moves via lsrow with per-wave in-order DS (no barrier needed).
// alpha = W[p][p] comes from the j=0 b128 chunk (.x, unused in updates).
__device__ __forceinline__ void sweep_invert(float (&Cm)[64], float* lsrow, int t) {
#pragma unroll 1
  for (int p = 0; p < 64; ++p) {
    lsrow[(t - p) & 63] = Cm[0];         // W[t][p]: permutation write, conflict-free
    float4 rp0 = ((const float4*)lsrow)[0];   // broadcast; .x == W[p][p]
    float alpha = rp0.x;
    float inva  = rcp_nr(alpha);
    bool  isP   = (t == p);
    float u0    = Cm[0] * inva;
    float u     = isP ? (1.0f - inva) : u0;   // per-lane sweep multiplier
    float last  = isP ? (-inva)       : u0;   // new column-p entry -> slot 63
    // j = 0 (no Cm[-1] write; rp0.x excluded from updates)
    Cm[0] = fmaf(-u, rp0.y, Cm[1]);
    Cm[1] = fmaf(-u, rp0.z, Cm[2]);
    Cm[2] = fmaf(-u, rp0.w, Cm[3]);
#pragma unroll
    for (int j = 1; j < 16; ++j) {
      float4 rp = ((const float4*)lsrow)[j];  // broadcast pivot row chunk
      int m0 = 4 * j;
      Cm[m0 - 1] = fmaf(-u, rp.x, Cm[m0]);
      Cm[m0 + 0] = fmaf(-u, rp.y, Cm[m0 + 1]);
      Cm[m0 + 1] = fmaf(-u, rp.z, Cm[m0 + 2]);
      Cm[m0 + 2] = fmaf(-u, rp.w, Cm[m0 + 3]);
    }
    Cm[63] = last;
  }
}

__global__ __launch_bounds__(64, 4) void fw_kernel(
    const float* __restrict__ xraw, const float* __restrict__ A,
    const float* __restrict__ b, const float* __restrict__ W1,
    const float* __restrict__ W1T, const float* __restrict__ w2,
    float* __restrict__ out) {
  const int n = blockIdx.x, t = threadIdx.x;
  const float* Ap = A + (size_t)n * 2048;

  __shared__ __align__(16) float lsA[32 * LDA];   // 8704 B, raw A (never rewritten)
  __shared__ __align__(16) float sbuf[256];       // 1024 B, multi-purpose
  float* lst1 = sbuf;            // [64]  ADMM t1 broadcast / sweep lsrow
  float* lsx  = sbuf + 64;       // [64]  ADMM x broadcast
  float* lsv2 = sbuf + 128;      // [32]  ADMM v2 broadcast
  float* lsrn = sbuf + 176;      // [32]  1/rownorm (LMO phase)
  // MLP phase reuses sbuf[0..255] as the u-vector.

  // ---- stage A into LDS (float4 both sides) ----
  const float4* Apv = (const float4*)Ap;
#pragma unroll
  for (int jj = 0; jj < 8; ++jj) {
    float4 a4 = Apv[t + 64 * jj];
    int k = (t >> 4) + 4 * jj;        // row
    int col = 4 * (t & 15);
    *((float4*)&lsA[k * LDA + col]) = a4;
  }
  WAVE_FENCE();

  const int r = t & 31, c0 = (t >> 5) << 5;

  // ================= anchor QP: build S, invert =================
  // S column t: (2+sig)I + A^T A - C2 * As^T As  (As = rows 28..31)
  float Cm[64];
#pragma unroll
  for (int i = 0; i < 64; ++i) Cm[i] = 0.f;
#pragma unroll 1
  for (int k = 0; k < 32; ++k) {
    float wk = (k < 28) ? 1.0f : (1.0f - C2);
    float ak = wk * lsA[k * LDA + t];  // spread read (dynamic k: LDS, not regs)
#pragma unroll
    for (int ii = 0; ii < 16; ++ii) {
      float4 a4 = *((const float4*)&lsA[k * LDA + 4 * ii]);  // broadcast
      Cm[4 * ii + 0] = fmaf(ak, a4.x, Cm[4 * ii + 0]);
      Cm[4 * ii + 1] = fmaf(ak, a4.y, Cm[4 * ii + 1]);
      Cm[4 * ii + 2] = fmaf(ak, a4.z, Cm[4 * ii + 2]);
      Cm[4 * ii + 3] = fmaf(ak, a4.w, Cm[4 * ii + 3]);
    }
  }
#pragma unroll
  for (int i = 0; i < 64; ++i) Cm[i] += (i == t) ? (2.0f + SIG) : 0.0f;

  sweep_invert(Cm, lst1, t);   // Cm[j] = -Sinv[t][j]

  float acol[32];
#pragma unroll
  for (int k = 0; k < 32; ++k) acol[k] = lsA[k * LDA + t];   // A[k][t], static idx

  const float xf = xraw[(size_t)n * 64 + t];
  const float bl = (t < 32) ? b[(size_t)n * 32 + t] : 0.f;

  // ================= anchor ADMM =================
  float x_loc = 0.f, s_loc = 0.f;
  float z1 = 0.f, y1 = 0.f;                       // rows t: l=0,u=inf
  float z2 = (t < 32) ? fminf(0.f, bl) : 0.f;     // rows 64+r: l=-inf,u=b (lanes<32)
  float y2 = 0.f;
  float z3 = 0.f, y3 = 0.f;                       // slack bound rows, LANES 28..31
                                                  // (co-located with s_loc)

#pragma unroll 1
  for (int it = 0; it < ITRS; ++it) {
    float v2 = z2 - y2;                            // meaningful lanes<32
    if (t < 32) lsv2[t] = v2;
    float v3 = z3 - y3;                            // lane-local (lanes 28..31)
    WAVE_FENCE();

    // rhs x-part: sig*x + xf + v1 + A^T v2   (v2 via LDS broadcast, 4-way ILP)
    float r10 = fmaf(SIG, x_loc, xf) + (z1 - y1);
    float r11 = 0.f, r12 = 0.f, r13 = 0.f;
#pragma unroll
    for (int kk = 0; kk < 8; ++kk) {
      float4 v4 = ((const float4*)lsv2)[kk];       // broadcast
      r10 = fmaf(acol[4 * kk + 0], v4.x, r10);
      r11 = fmaf(acol[4 * kk + 1], v4.y, r11);
      r12 = fmaf(acol[4 * kk + 2], v4.z, r12);
      r13 = fmaf(acol[4 * kk + 3], v4.w, r13);
    }
    float r1 = (r10 + r11) + (r12 + r13);

    // rhs s-part (meaningful lanes 28..31): sig*s - v[92+i] + v[96+i]
    float r2v = fmaf(SIG, s_loc, v3 - v2);

    // t1 = r1 + C2 * As^T r2   (4 cross-lane scalars, constant lanes)
    float acc = 0.f;
    acc = fmaf(acol[28], rl(r2v, 28), acc);
    acc = fmaf(acol[29], rl(r2v, 29), acc);
    acc = fmaf(acol[30], rl(r2v, 30), acc);
    acc = fmaf(acol[31], rl(r2v, 31), acc);
    lst1[t] = fmaf(C2, acc, r1);
    WAVE_FENCE();

    // x = Sinv * t1 = -(W * t1): minus folds into FMA input modifier (free)
    float xn0 = 0.f, xn1 = 0.f, xn2 = 0.f, xn3 = 0.f;
#pragma unroll
    for (int jj = 0; jj < 16; ++jj) {
      float4 t4 = ((const float4*)lst1)[jj];       // broadcast
      xn0 = fmaf(-Cm[4 * jj + 0], t4.x, xn0);
      xn1 = fmaf(-Cm[4 * jj + 1], t4.y, xn1);
      xn2 = fmaf(-Cm[4 * jj + 2], t4.z, xn2);
      xn3 = fmaf(-Cm[4 * jj + 3], t4.w, xn3);
    }
    float xn = (xn0 + xn1) + (xn2 + xn3);
    x_loc = xn;
    lsx[t] = xn;
    WAVE_FENCE();

    // (A x)[r]: A row from LDS (spread b128), x via 2-addr broadcast reads
    float pa0 = 0.f, pa1 = 0.f, pa2 = 0.f, pa3 = 0.f;
#pragma unroll
    for (int jj = 0; jj < 8; ++jj) {
      float4 x4 = ((const float4*)(lsx + c0))[jj];
      float4 a4 = *((const float4*)&lsA[r * LDA + c0 + 4 * jj]);
      pa0 = fmaf(a4.x, x4.x, pa0);
      pa1 = fmaf(a4.y, x4.y, pa1);
      pa2 = fmaf(a4.z, x4.z, pa2);
      pa3 = fmaf(a4.w, x4.w, pa3);
    }
    float pa = (pa0 + pa1) + (pa2 + pa3);
    pa = xor32_sum(pa);                            // VALU-pipe fold

    // s = C2*(r2 + As x)  (meaningful lanes 28..31)
    float s_new = C2 * (r2v + pa);

    // z,y updates
    { float q1 = xn + y1; z1 = fmaxf(q1, 0.f); y1 = q1 - z1; }
    if (t < 32) {
      float Cx2 = pa - ((t >= 28) ? s_new : 0.f);  // rows 92..95: As x - s
      float q2 = Cx2 + y2; z2 = fminf(q2, bl); y2 = q2 - z2;
    }
    s_loc = s_new;
    { float q3 = s_new + y3; z3 = fmaxf(q3, 0.f); y3 = q3 - z3; }  // lane-local
  }
  const float xfeas_r = x_loc;   // lsx still holds x_feas

  // ================= MLP gradient =================
  float4 hacc = make_float4(0.f, 0.f, 0.f, 0.f);
  const float4* W1v = (const float4*)W1;
#pragma unroll 2
  for (int j4 = 0; j4 < 16; ++j4) {
    float4 x4 = ((const float4*)lsx)[j4];          // broadcast
    float xj[4] = {x4.x, x4.y, x4.z, x4.w};
#pragma unroll
    for (int jj = 0; jj < 4; ++jj) {
      float4 w = W1v[(4 * j4 + jj) * 64 + t];
      hacc.x = fmaf(xj[jj], w.x, hacc.x);
      hacc.y = fmaf(xj[jj], w.y, hacc.y);
      hacc.z = fmaf(xj[jj], w.z, hacc.z);
      hacc.w = fmaf(xj[jj], w.w, hacc.w);
    }
  }
  float4 wv = ((const float4*)w2)[t];
  float hx, u0, u1, u2, u3;
  hx = tanhf(hacc.x); u0 = (1.f - hx * hx) * wv.x;
  hx = tanhf(hacc.y); u1 = (1.f - hx * hx) * wv.y;
  hx = tanhf(hacc.z); u2 = (1.f - hx * hx) * wv.z;
  hx = tanhf(hacc.w); u3 = (1.f - hx * hx) * wv.w;
  WAVE_FENCE();                          // lsx readers done (in-order DS)
  ((float4*)sbuf)[t] = make_float4(u0, u1, u2, u3);   // sbuf = u[256]
  WAVE_FENCE();

  // g[t] = sum_c W1[t][c]*u[c]; W1T pre-packed: W1T4[c4*64+t] = W1[t][4c4..4c4+3]
  float g0 = 0.f, g1 = 0.f, g2 = 0.f, g3 = 0.f;
  const float4* L4 = (const float4*)W1T;
#pragma unroll 4
  for (int c4 = 0; c4 < 64; ++c4) {
    float4 u4 = ((const float4*)sbuf)[c4];   // broadcast
    float4 w4 = L4[c4 * 64 + t];             // coalesced
    g0 = fmaf(w4.x, u4.x, g0);
    g1 = fmaf(w4.y, u4.y, g1);
    g2 = fmaf(w4.z, u4.z, g2);
    g3 = fmaf(w4.w, u4.w, g3);
  }
  const float gl = (g0 + g1) + (g2 + g3);

  // ================= row norms (rows from LDS) =================
  float pr0 = 0.f, pr1 = 0.f, pr2 = 0.f, pr3 = 0.f;
#pragma unroll
  for (int jj = 0; jj < 8; ++jj) {
    float4 a4 = *((const float4*)&lsA[r * LDA + c0 + 4 * jj]);
    pr0 = fmaf(a4.x, a4.x, pr0);
    pr1 = fmaf(a4.y, a4.y, pr1);
    pr2 = fmaf(a4.z, a4.z, pr2);
    pr3 = fmaf(a4.w, a4.w, pr3);
  }
  float pr = (pr0 + pr1) + (pr2 + pr3);
  pr = xor32_sum(pr);                      // VALU-pipe fold
  // Every lane now holds the full row-r norm: rcp_r is LANE-LOCAL
  // (same ops as the old lsrn[r] path -> same bits).
  const float rcp_r = 1.0f / fmaxf(sqrtf(pr), 1e-12f);
  const float bn = (t < 32) ? bl * rcp_r : 0.f;
  WAVE_FENCE();                          // u readers done before lsrn write
  if (t < 32) lsrn[t] = rcp_r;           // k-indexed consumers only
  WAVE_FENCE();

  // normalized columns in regs: acol STILL holds raw A[k][t] (never written
  // since anchor) -> in-register scale, lsrn via 8 b128 broadcasts.
#pragma unroll
  for (int kk = 0; kk < 8; ++kk) {
    float4 rn4 = ((const float4*)lsrn)[kk];   // broadcast
    acol[4 * kk + 0] *= rn4.x;
    acol[4 * kk + 1] *= rn4.y;
    acol[4 * kk + 2] *= rn4.z;
    acol[4 * kk + 3] *= rn4.w;
  }

  // ================= LMO QP: build M, invert =================
  // M col t: (1+eps+sig)I + sum_k rcp_k^2 A[k][t] A[k][:]
#pragma unroll
  for (int i = 0; i < 64; ++i) Cm[i] = 0.f;
#pragma unroll 1
  for (int k = 0; k < 32; ++k) {
    float rn = lsrn[k];                  // broadcast (dynamic k: LDS)
    float ak = lsA[k * LDA + t] * rn * rn;
#pragma unroll
    for (int ii = 0; ii < 16; ++ii) {
      float4 a4 = *((const float4*)&lsA[k * LDA + 4 * ii]);  // raw row, broadcast
      Cm[4 * ii + 0] = fmaf(ak, a4.x, Cm[4 * ii + 0]);
      Cm[4 * ii + 1] = fmaf(ak, a4.y, Cm[4 * ii + 1]);
      Cm[4 * ii + 2] = fmaf(ak, a4.z, Cm[4 * ii + 2]);
      Cm[4 * ii + 3] = fmaf(ak, a4.w, Cm[4 * ii + 3]);
    }
  }
#pragma unroll
  for (int i = 0; i < 64; ++i) Cm[i] += (i == t) ? (1.0f + 1e-4f + SIG) : 0.0f;

  sweep_invert(Cm, lst1, t);   // Cm[j] = -Minv[t][j]

  // ================= LMO ADMM =================
  x_loc = 0.f; z1 = 0.f; y1 = 0.f;
  z2 = (t < 32) ? fminf(0.f, bn) : 0.f;
  y2 = 0.f;

#pragma unroll 1
  for (int it = 0; it < ITRS_LMO; ++it) {
    if (t < 32) lsv2[t] = z2 - y2;
    WAVE_FENCE();
    float r10 = fmaf(SIG, x_loc, gl) + (z1 - y1);
    float r11 = 0.f, r12 = 0.f, r13 = 0.f;
#pragma unroll
    for (int kk = 0; kk < 8; ++kk) {
      float4 v4 = ((const float4*)lsv2)[kk];       // broadcast
      r10 = fmaf(acol[4 * kk + 0], v4.x, r10);
      r11 = fmaf(acol[4 * kk + 1], v4.y, r11);
      r12 = fmaf(acol[4 * kk + 2], v4.z, r12);
      r13 = fmaf(acol[4 * kk + 3], v4.w, r13);
    }
    lst1[t] = (r10 + r11) + (r12 + r13);
    WAVE_FENCE();

    float xn0 = 0.f, xn1 = 0.f, xn2 = 0.f, xn3 = 0.f;
#pragma unroll
    for (int jj = 0; jj < 16; ++jj) {
      float4 t4 = ((const float4*)lst1)[jj];       // broadcast
      xn0 = fmaf(-Cm[4 * jj + 0], t4.x, xn0);
      xn1 = fmaf(-Cm[4 * jj + 1], t4.y, xn1);
      xn2 = fmaf(-Cm[4 * jj + 2], t4.z, xn2);
      xn3 = fmaf(-Cm[4 * jj + 3], t4.w, xn3);
    }
    float xn = (xn0 + xn1) + (xn2 + xn3);
    x_loc = xn;
    lsx[t] = xn;
    WAVE_FENCE();

    // (An x)[r] = rcp_r * (Araw[r] . x)
    float pa0 = 0.f, pa1 = 0.f, pa2 = 0.f, pa3 = 0.f;
#pragma unroll
    for (int jj = 0; jj < 8; ++jj) {
      float4 x4 = ((const float4*)(lsx + c0))[jj];
      float4 a4 = *((const float4*)&lsA[r * LDA + c0 + 4 * jj]);
      pa0 = fmaf(a4.x, x4.x, pa0);
      pa1 = fmaf(a4.y, x4.y, pa1);
      pa2 = fmaf(a4.z, x4.z, pa2);
      pa3 = fmaf(a4.w, x4.w, pa3);
    }
    float pa = (pa0 + pa1) + (pa2 + pa3);
    pa = xor32_sum(pa);                            // VALU-pipe fold
    pa *= rcp_r;

    { float q1 = xn + y1; z1 = fmaxf(q1, 0.f); y1 = q1 - z1; }
    if (t < 32) { float q2 = pa + y2; z2 = fminf(q2, bn); y2 = q2 - z2; }
  }

  out[(size_t)n * 64 + t] = fmaf(0.1f, x_loc, 0.9f * xfeas_r);
}

// ---- W1 re-pack: W1T[c4*256 + t*4 + j] = W1[t*256 + 4*c4 + j] (once) ----
__global__ void w1t_kernel(const float* __restrict__ W1, float* __restrict__ W1T) {
  int idx = blockIdx.x * 256 + threadIdx.x;
  if (idx < 64 * 256) {
    int c4 = idx >> 8, rem = idx & 255, tt = rem >> 2, j = rem & 3;
    W1T[idx] = W1[tt * 256 + 4 * c4 + j];
  }
}

extern "C" void kernel_launch(void* const* d_in, const int* in_sizes, int n_in,
                              void* d_out, int out_size, void* d_ws, size_t ws_size,
                              hipStream_t stream) {
  const float* xraw = (const float*)d_in[0];  // [N,64]
  const float* A    = (const float*)d_in[1];  // [N,32,64]
  const float* b    = (const float*)d_in[2];  // [N,32]
  const float* W1   = (const float*)d_in[3];  // [64,256]
  const float* w2   = (const float*)d_in[4];  // [256]
  float* out = (float*)d_out;

  const int nprob = in_sizes[0] / 64;
  float* W1T = (float*)d_ws;                  // 16384 floats

  w1t_kernel<<<64, 256, 0, stream>>>(W1, W1T);
  fw_kernel<<<nprob, 64, 0, stream>>>(xraw, A, b, W1, W1T, w2, out);
}

// Round 9
// 459.582 us; speedup vs baseline: 1.1431x; 1.1431x over previous
//
#include <hip/hip_runtime.h>
#include <math.h>

// FrankWolfePolicyImprovement, fused: 4096 problems, one wave (64 lanes) each.
// Phases (single kernel, A resident in LDS throughout):
//   1. anchor QP  (Schur-reduced d=68 ADMM, 80 it, Sinv rows in VGPRs)
//   2. tanh MLP gradient
//   3. LMO QP on row-normalized A (normalization folded into registers)
//   4. blend + store
//
// Round-15: REVERT round-14's DS micro-pass (regressed 533->605us, -13%).
// Post-mortem: (b) in-register acol rescale extended acol's live range
// across the MLP phase (+32 live VGPRs at the 124/128 boundary) ->
// global-load ILP throttled (VALUBusy 76->66, FETCH +8MB from degraded L2
// ordering on W1/W1T streams). THIRD confirmation of the register-boundary
// rule: any live-range extension at 124/128 costs more than the DS ops it
// saves -- round 1-2 (spill/starve), round 14 (ILP throttle).
// This source == round-13 kernel exactly (measured 461.2us, best).
//
// FINAL STATE. Structural floor, evidence:
//  - DS-issue-bound: time tracks weighted DS-op count across 9 experiments;
//    ~43 DS/ADMM-iter is within ~2 ops of minimal for the 64-lane-
//    cooperative decomposition (LDS round-trips ARE the gather/reduce).
//  - Bank conflicts 0; HBM 2% of peak; VALU 76% (subordinate pipes).
//  - Occupancy grid-structural: 4096 blocks = exactly 16/CU = LDS capacity.
//  - Registers: 124/128 live; every hoist variant measured-dead.
//  - Iterations pinned: ref is the 80-it ADMM ITERATE (64-it fails 3.2x).
//
// Measured-dead levers (do not retry):
//  - A-rows in VGPRs; readlane broadcasts (SGPR RAW hazard ~12cyc);
//    occupancy changes in either direction; iteration truncation;
//    acol live-range extension; sweep alpha-fold restructure.
//
//  - NO dynamic indexing into register arrays (demotes array to scratch/AGPR).
//  - All wave-internal broadcasts on the LDS pipe (wave-uniform float4 reads).
//  - WAVE_FENCE instead of __syncthreads: single-wave blocks + per-wave
//    in-order DS (HW-verified rounds 7-9).
//  - xor-32 folds on VALU via v_permlane32_swap_b32 (round-13 win, -2.5%).
//  - Slack state z3,y3 co-located on lanes 28..31 (round-13 win).
//  - Inversion via symmetric sweep operator: pivot row == pivot col, lane-local
//    after rotation; broadcast = 1 conflict-free ds_write + 16 b128 reads.
//    After 64 sweeps W = -S^-1; minus folds into the x-update FMA modifier.

constexpr float SIG  = 1e-6f;
constexpr float C2   = 1.0f / (4.0f + 1e-6f);   // 1/(4+sigma): slack Schur diag
constexpr int   ITRS = 80;                       // anchor ADMM iterations (pinned)
constexpr int   ITRS_LMO = 80;                   // LMO ADMM iterations (pinned)
constexpr int   LDA  = 68;                       // LDS stride for A (16B-aligned rows)

// Compiler-only ordering fence. Valid because each block is ONE wave and DS
// ops execute in order within a wave (RAW through LDS needs no barrier).
#define WAVE_FENCE() asm volatile("" ::: "memory")

typedef unsigned int uint2v __attribute__((ext_vector_type(2)));

__device__ __forceinline__ float rl(float v, int lane) {
  return __uint_as_float(__builtin_amdgcn_readlane(__float_as_uint(v), lane));
}

// Full-wave lane<->lane+32 fold on the VALU pipe (v_permlane32_swap_b32).
// With equal operands the swap yields [v_lo,v_lo] and [v_hi,v_hi]; their sum
// equals v + shfl_xor(v,32) on every lane, bit-identically.
__device__ __forceinline__ float xor32_sum(float v) {
  unsigned u = __float_as_uint(v);
  uint2v rr = __builtin_amdgcn_permlane32_swap(u, u, false, false);
  return __uint_as_float(rr[0]) + __uint_as_float(rr[1]);
}

// v_rcp_f32 + one Newton step: ~full fp32 precision reciprocal.
__device__ __forceinline__ float rcp_nr(float x) {
  float r = __builtin_amdgcn_rcpf(x);
  return r * fmaf(-x, r, 2.0f);
}

// Symmetric sweep-operator inversion. Lane t holds row t (== col t) of the
// symmetric working matrix W, rotated so the current pivot is local index 0.
// After 64 sweeps: Cm[j] = -Sinv[t][j]. Single-wave blocks; cross-lane data
// moves via lsrow with per-wave in-order DS (no barrier needed).
__device__ __forceinline__ void sweep_invert(float (&Cm)[64], float* lsrow, int t) {
#pragma unroll 1
  for (int p = 0; p < 64; ++p) {
    lsrow[(t - p) & 63] = Cm[0];         // W[t][p]: permutation write, conflict-free
    float alpha = lsrow[0];              // broadcast: W[p][p]
    float inva  = rcp_nr(alpha);
    bool  isP   = (t == p);
    float u0    = Cm[0] * inva;
    float u     = isP ? (1.0f - inva) : u0;   // per-lane sweep multiplier
    float last  = isP ? (-inva)       : u0;   // new column-p entry -> slot 63
#pragma unroll
    for (int j = 0; j < 16; ++j) {
      float4 rp = ((const float4*)lsrow)[j];  // broadcast pivot row chunk
      int m0 = 4 * j;
      if (j) Cm[m0 - 1] = fmaf(-u, rp.x, Cm[m0]);
      Cm[m0 + 0] = fmaf(-u, rp.y, Cm[m0 + 1]);
      Cm[m0 + 1] = fmaf(-u, rp.z, Cm[m0 + 2]);
      Cm[m0 + 2] = fmaf(-u, rp.w, Cm[m0 + 3]);
    }
    Cm[63] = last;
  }
}

__global__ __launch_bounds__(64, 4) void fw_kernel(
    const float* __restrict__ xraw, const float* __restrict__ A,
    const float* __restrict__ b, const float* __restrict__ W1,
    const float* __restrict__ W1T, const float* __restrict__ w2,
    float* __restrict__ out) {
  const int n = blockIdx.x, t = threadIdx.x;
  const float* Ap = A + (size_t)n * 2048;

  __shared__ __align__(16) float lsA[32 * LDA];   // 8704 B, raw A (never rewritten)
  __shared__ __align__(16) float sbuf[256];       // 1024 B, multi-purpose
  float* lst1 = sbuf;            // [64]  ADMM t1 broadcast / sweep lsrow
  float* lsx  = sbuf + 64;       // [64]  ADMM x broadcast
  float* lsv2 = sbuf + 128;      // [32]  ADMM v2 broadcast
  float* lsrn = sbuf + 176;      // [32]  1/rownorm (LMO phase)
  // MLP phase reuses sbuf[0..255] as the u-vector.

  // ---- stage A into LDS (float4 both sides) ----
  const float4* Apv = (const float4*)Ap;
#pragma unroll
  for (int jj = 0; jj < 8; ++jj) {
    float4 a4 = Apv[t + 64 * jj];
    int k = (t >> 4) + 4 * jj;        // row
    int col = 4 * (t & 15);
    *((float4*)&lsA[k * LDA + col]) = a4;
  }
  WAVE_FENCE();

  const int r = t & 31, c0 = (t >> 5) << 5;

  // ================= anchor QP: build S, invert =================
  // S column t: (2+sig)I + A^T A - C2 * As^T As  (As = rows 28..31)
  float Cm[64];
#pragma unroll
  for (int i = 0; i < 64; ++i) Cm[i] = 0.f;
#pragma unroll 1
  for (int k = 0; k < 32; ++k) {
    float wk = (k < 28) ? 1.0f : (1.0f - C2);
    float ak = wk * lsA[k * LDA + t];  // spread read (dynamic k: LDS, not regs)
#pragma unroll
    for (int ii = 0; ii < 16; ++ii) {
      float4 a4 = *((const float4*)&lsA[k * LDA + 4 * ii]);  // broadcast
      Cm[4 * ii + 0] = fmaf(ak, a4.x, Cm[4 * ii + 0]);
      Cm[4 * ii + 1] = fmaf(ak, a4.y, Cm[4 * ii + 1]);
      Cm[4 * ii + 2] = fmaf(ak, a4.z, Cm[4 * ii + 2]);
      Cm[4 * ii + 3] = fmaf(ak, a4.w, Cm[4 * ii + 3]);
    }
  }
#pragma unroll
  for (int i = 0; i < 64; ++i) Cm[i] += (i == t) ? (2.0f + SIG) : 0.0f;

  sweep_invert(Cm, lst1, t);   // Cm[j] = -Sinv[t][j]

  float acol[32];
#pragma unroll
  for (int k = 0; k < 32; ++k) acol[k] = lsA[k * LDA + t];   // A[k][t], static idx

  const float xf = xraw[(size_t)n * 64 + t];
  const float bl = (t < 32) ? b[(size_t)n * 32 + t] : 0.f;

  // ================= anchor ADMM =================
  float x_loc = 0.f, s_loc = 0.f;
  float z1 = 0.f, y1 = 0.f;                       // rows t: l=0,u=inf
  float z2 = (t < 32) ? fminf(0.f, bl) : 0.f;     // rows 64+r: l=-inf,u=b (lanes<32)
  float y2 = 0.f;
  float z3 = 0.f, y3 = 0.f;                       // slack bound rows, LANES 28..31
                                                  // (co-located with s_loc)

#pragma unroll 1
  for (int it = 0; it < ITRS; ++it) {
    float v2 = z2 - y2;                            // meaningful lanes<32
    if (t < 32) lsv2[t] = v2;
    float v3 = z3 - y3;                            // lane-local (lanes 28..31)
    WAVE_FENCE();

    // rhs x-part: sig*x + xf + v1 + A^T v2   (v2 via LDS broadcast, 4-way ILP)
    float r10 = fmaf(SIG, x_loc, xf) + (z1 - y1);
    float r11 = 0.f, r12 = 0.f, r13 = 0.f;
#pragma unroll
    for (int kk = 0; kk < 8; ++kk) {
      float4 v4 = ((const float4*)lsv2)[kk];       // broadcast
      r10 = fmaf(acol[4 * kk + 0], v4.x, r10);
      r11 = fmaf(acol[4 * kk + 1], v4.y, r11);
      r12 = fmaf(acol[4 * kk + 2], v4.z, r12);
      r13 = fmaf(acol[4 * kk + 3], v4.w, r13);
    }
    float r1 = (r10 + r11) + (r12 + r13);

    // rhs s-part (meaningful lanes 28..31): sig*s - v[92+i] + v[96+i]
    float r2v = fmaf(SIG, s_loc, v3 - v2);

    // t1 = r1 + C2 * As^T r2   (4 cross-lane scalars, constant lanes)
    float acc = 0.f;
    acc = fmaf(acol[28], rl(r2v, 28), acc);
    acc = fmaf(acol[29], rl(r2v, 29), acc);
    acc = fmaf(acol[30], rl(r2v, 30), acc);
    acc = fmaf(acol[31], rl(r2v, 31), acc);
    lst1[t] = fmaf(C2, acc, r1);
    WAVE_FENCE();

    // x = Sinv * t1 = -(W * t1): minus folds into FMA input modifier (free)
    float xn0 = 0.f, xn1 = 0.f, xn2 = 0.f, xn3 = 0.f;
#pragma unroll
    for (int jj = 0; jj < 16; ++jj) {
      float4 t4 = ((const float4*)lst1)[jj];       // broadcast
      xn0 = fmaf(-Cm[4 * jj + 0], t4.x, xn0);
      xn1 = fmaf(-Cm[4 * jj + 1], t4.y, xn1);
      xn2 = fmaf(-Cm[4 * jj + 2], t4.z, xn2);
      xn3 = fmaf(-Cm[4 * jj + 3], t4.w, xn3);
    }
    float xn = (xn0 + xn1) + (xn2 + xn3);
    x_loc = xn;
    lsx[t] = xn;
    WAVE_FENCE();

    // (A x)[r]: A row from LDS (spread b128), x via 2-addr broadcast reads
    float pa0 = 0.f, pa1 = 0.f, pa2 = 0.f, pa3 = 0.f;
#pragma unroll
    for (int jj = 0; jj < 8; ++jj) {
      float4 x4 = ((const float4*)(lsx + c0))[jj];
      float4 a4 = *((const float4*)&lsA[r * LDA + c0 + 4 * jj]);
      pa0 = fmaf(a4.x, x4.x, pa0);
      pa1 = fmaf(a4.y, x4.y, pa1);
      pa2 = fmaf(a4.z, x4.z, pa2);
      pa3 = fmaf(a4.w, x4.w, pa3);
    }
    float pa = (pa0 + pa1) + (pa2 + pa3);
    pa = xor32_sum(pa);                            // VALU-pipe fold

    // s = C2*(r2 + As x)  (meaningful lanes 28..31)
    float s_new = C2 * (r2v + pa);

    // z,y updates
    { float q1 = xn + y1; z1 = fmaxf(q1, 0.f); y1 = q1 - z1; }
    if (t < 32) {
      float Cx2 = pa - ((t >= 28) ? s_new : 0.f);  // rows 92..95: As x - s
      float q2 = Cx2 + y2; z2 = fminf(q2, bl); y2 = q2 - z2;
    }
    s_loc = s_new;
    { float q3 = s_new + y3; z3 = fmaxf(q3, 0.f); y3 = q3 - z3; }  // lane-local
  }
  const float xfeas_r = x_loc;   // lsx still holds x_feas

  // ================= MLP gradient =================
  float4 hacc = make_float4(0.f, 0.f, 0.f, 0.f);
  const float4* W1v = (const float4*)W1;
#pragma unroll 2
  for (int j4 = 0; j4 < 16; ++j4) {
    float4 x4 = ((const float4*)lsx)[j4];          // broadcast
    float xj[4] = {x4.x, x4.y, x4.z, x4.w};
#pragma unroll
    for (int jj = 0; jj < 4; ++jj) {
      float4 w = W1v[(4 * j4 + jj) * 64 + t];
      hacc.x = fmaf(xj[jj], w.x, hacc.x);
      hacc.y = fmaf(xj[jj], w.y, hacc.y);
      hacc.z = fmaf(xj[jj], w.z, hacc.z);
      hacc.w = fmaf(xj[jj], w.w, hacc.w);
    }
  }
  float4 wv = ((const float4*)w2)[t];
  float hx, u0, u1, u2, u3;
  hx = tanhf(hacc.x); u0 = (1.f - hx * hx) * wv.x;
  hx = tanhf(hacc.y); u1 = (1.f - hx * hx) * wv.y;
  hx = tanhf(hacc.z); u2 = (1.f - hx * hx) * wv.z;
  hx = tanhf(hacc.w); u3 = (1.f - hx * hx) * wv.w;
  WAVE_FENCE();                          // lsx readers done (in-order DS)
  ((float4*)sbuf)[t] = make_float4(u0, u1, u2, u3);   // sbuf = u[256]
  WAVE_FENCE();

  // g[t] = sum_c W1[t][c]*u[c]; W1T pre-packed: W1T4[c4*64+t] = W1[t][4c4..4c4+3]
  float g0 = 0.f, g1 = 0.f, g2 = 0.f, g3 = 0.f;
  const float4* L4 = (const float4*)W1T;
#pragma unroll 4
  for (int c4 = 0; c4 < 64; ++c4) {
    float4 u4 = ((const float4*)sbuf)[c4];   // broadcast
    float4 w4 = L4[c4 * 64 + t];             // coalesced
    g0 = fmaf(w4.x, u4.x, g0);
    g1 = fmaf(w4.y, u4.y, g1);
    g2 = fmaf(w4.z, u4.z, g2);
    g3 = fmaf(w4.w, u4.w, g3);
  }
  const float gl = (g0 + g1) + (g2 + g3);

  // ================= row norms (rows from LDS) =================
  float pr0 = 0.f, pr1 = 0.f, pr2 = 0.f, pr3 = 0.f;
#pragma unroll
  for (int jj = 0; jj < 8; ++jj) {
    float4 a4 = *((const float4*)&lsA[r * LDA + c0 + 4 * jj]);
    pr0 = fmaf(a4.x, a4.x, pr0);
    pr1 = fmaf(a4.y, a4.y, pr1);
    pr2 = fmaf(a4.z, a4.z, pr2);
    pr3 = fmaf(a4.w, a4.w, pr3);
  }
  float pr = (pr0 + pr1) + (pr2 + pr3);
  pr = xor32_sum(pr);                      // VALU-pipe fold
  WAVE_FENCE();                          // u readers done before lsrn write
  if (t < 32) lsrn[t] = 1.0f / fmaxf(sqrtf(pr), 1e-12f);
  WAVE_FENCE();

  const float rcp_r = lsrn[r];           // spread read, conflict-free
  const float bn = (t < 32) ? bl * rcp_r : 0.f;

  // normalized columns in regs (static indices; lsA stays raw)
#pragma unroll
  for (int k = 0; k < 32; ++k) acol[k] = lsA[k * LDA + t] * lsrn[k];

  // ================= LMO QP: build M, invert =================
  // M col t: (1+eps+sig)I + sum_k rcp_k^2 A[k][t] A[k][:]
#pragma unroll
  for (int i = 0; i < 64; ++i) Cm[i] = 0.f;
#pragma unroll 1
  for (int k = 0; k < 32; ++k) {
    float rn = lsrn[k];                  // broadcast (dynamic k: LDS)
    float ak = lsA[k * LDA + t] * rn * rn;
#pragma unroll
    for (int ii = 0; ii < 16; ++ii) {
      float4 a4 = *((const float4*)&lsA[k * LDA + 4 * ii]);  // raw row, broadcast
      Cm[4 * ii + 0] = fmaf(ak, a4.x, Cm[4 * ii + 0]);
      Cm[4 * ii + 1] = fmaf(ak, a4.y, Cm[4 * ii + 1]);
      Cm[4 * ii + 2] = fmaf(ak, a4.z, Cm[4 * ii + 2]);
      Cm[4 * ii + 3] = fmaf(ak, a4.w, Cm[4 * ii + 3]);
    }
  }
#pragma unroll
  for (int i = 0; i < 64; ++i) Cm[i] += (i == t) ? (1.0f + 1e-4f + SIG) : 0.0f;

  sweep_invert(Cm, lst1, t);   // Cm[j] = -Minv[t][j]

  // ================= LMO ADMM =================
  x_loc = 0.f; z1 = 0.f; y1 = 0.f;
  z2 = (t < 32) ? fminf(0.f, bn) : 0.f;
  y2 = 0.f;

#pragma unroll 1
  for (int it = 0; it < ITRS_LMO; ++it) {
    if (t < 32) lsv2[t] = z2 - y2;
    WAVE_FENCE();
    float r10 = fmaf(SIG, x_loc, gl) + (z1 - y1);
    float r11 = 0.f, r12 = 0.f, r13 = 0.f;
#pragma unroll
    for (int kk = 0; kk < 8; ++kk) {
      float4 v4 = ((const float4*)lsv2)[kk];       // broadcast
      r10 = fmaf(acol[4 * kk + 0], v4.x, r10);
      r11 = fmaf(acol[4 * kk + 1], v4.y, r11);
      r12 = fmaf(acol[4 * kk + 2], v4.z, r12);
      r13 = fmaf(acol[4 * kk + 3], v4.w, r13);
    }
    lst1[t] = (r10 + r11) + (r12 + r13);
    WAVE_FENCE();

    float xn0 = 0.f, xn1 = 0.f, xn2 = 0.f, xn3 = 0.f;
#pragma unroll
    for (int jj = 0; jj < 16; ++jj) {
      float4 t4 = ((const float4*)lst1)[jj];       // broadcast
      xn0 = fmaf(-Cm[4 * jj + 0], t4.x, xn0);
      xn1 = fmaf(-Cm[4 * jj + 1], t4.y, xn1);
      xn2 = fmaf(-Cm[4 * jj + 2], t4.z, xn2);
      xn3 = fmaf(-Cm[4 * jj + 3], t4.w, xn3);
    }
    float xn = (xn0 + xn1) + (xn2 + xn3);
    x_loc = xn;
    lsx[t] = xn;
    WAVE_FENCE();

    // (An x)[r] = rcp_r * (Araw[r] . x)
    float pa0 = 0.f, pa1 = 0.f, pa2 = 0.f, pa3 = 0.f;
#pragma unroll
    for (int jj = 0; jj < 8; ++jj) {
      float4 x4 = ((const float4*)(lsx + c0))[jj];
      float4 a4 = *((const float4*)&lsA[r * LDA + c0 + 4 * jj]);
      pa0 = fmaf(a4.x, x4.x, pa0);
      pa1 = fmaf(a4.y, x4.y, pa1);
      pa2 = fmaf(a4.z, x4.z, pa2);
      pa3 = fmaf(a4.w, x4.w, pa3);
    }
    float pa = (pa0 + pa1) + (pa2 + pa3);
    pa = xor32_sum(pa);                            // VALU-pipe fold
    pa *= rcp_r;

    { float q1 = xn + y1; z1 = fmaxf(q1, 0.f); y1 = q1 - z1; }
    if (t < 32) { float q2 = pa + y2; z2 = fminf(q2, bn); y2 = q2 - z2; }
  }

  out[(size_t)n * 64 + t] = fmaf(0.1f, x_loc, 0.9f * xfeas_r);
}

// ---- W1 re-pack: W1T[c4*256 + t*4 + j] = W1[t*256 + 4*c4 + j] (once) ----
__global__ void w1t_kernel(const float* __restrict__ W1, float* __restrict__ W1T) {
  int idx = blockIdx.x * 256 + threadIdx.x;
  if (idx < 64 * 256) {
    int c4 = idx >> 8, rem = idx & 255, tt = rem >> 2, j = rem & 3;
    W1T[idx] = W1[tt * 256 + 4 * c4 + j];
  }
}

extern "C" void kernel_launch(void* const* d_in, const int* in_sizes, int n_in,
                              void* d_out, int out_size, void* d_ws, size_t ws_size,
                              hipStream_t stream) {
  const float* xraw = (const float*)d_in[0];  // [N,64]
  const float* A    = (const float*)d_in[1];  // [N,32,64]
  const float* b    = (const float*)d_in[2];  // [N,32]
  const float* W1   = (const float*)d_in[3];  // [64,256]
  const float* w2   = (const float*)d_in[4];  // [256]
  float* out = (float*)d_out;

  const int nprob = in_sizes[0] / 64;
  float* W1T = (float*)d_ws;                  // 16384 floats

  w1t_kernel<<<64, 256, 0, stream>>>(W1, W1T);
  fw_kernel<<<nprob, 64, 0, stream>>>(xraw, A, b, W1, W1T, w2, out);
}